// Round 1
// baseline (108.151 us; speedup 1.0000x reference)
//
#include <hip/hip_runtime.h>
#include <hip/hip_bf16.h>
#include <stdint.h>

// Problem: B=16384, D=256, E=16, K=4, C=10
// out = [market_probs (B*C) | all_probs (E*B*C) | gate_probs (B*E)], fp32
// ws layout (bytes):
//   xhat bf16 [B][256]           @ 0        (8388608)
//   w1t  bf16 [E][256 n][256 k]  @ 8388608  (2097152)   w1t[e][n][k] = ln_g[e][k]*w1[e][k][n]
//   w2t  bf16 [E][16 c][256 h]   @ 10485760 (131072)    zero-padded c=10..15
//   b1p  f32  [E][256]           @ 10616832 (16384)     b1 + ln_b @ w1
//   tki  int  [B][4]             @ 10633216 (262144)
//   tkw  f32  [B][4]             @ 10895360 (262144)
// total ~10.65 MB

typedef __bf16 bf16;
typedef __bf16 bf16x8 __attribute__((ext_vector_type(8)));
typedef __bf16 bf16x4 __attribute__((ext_vector_type(4)));
typedef float  f32x4  __attribute__((ext_vector_type(4)));

#define XHAT_OFF 0UL
#define W1T_OFF  8388608UL
#define W2T_OFF  10485760UL
#define B1P_OFF  10616832UL
#define TKI_OFF  10633216UL
#define TKW_OFF  10895360UL

#define APROBS_OFF 163840UL
#define GATE_OFF   2785280UL

#define LOG2E 1.4426950408889634f

__device__ __forceinline__ void gl_lds16(const void* g, void* l) {
  __builtin_amdgcn_global_load_lds((const __attribute__((address_space(1))) void*)g,
                                   (__attribute__((address_space(3))) void*)l, 16, 0, 0);
}

// tanh-approx GELU via exp2: gelu(x) = x - x * 1/(1+exp2(x*(c1+c2*x^2)))
// max abs err vs exact (erf) gelu ~1e-3; safe for large |x| (exp2->0/inf).
__device__ __forceinline__ float gelu_f(float x) {
  float s = x * x;
  float z = x * (2.3022082f + 0.10294324f * s);
  float t = __builtin_amdgcn_exp2f(z);
  float r = __builtin_amdgcn_rcpf(t + 1.0f);
  return x - x * r;
}

// ---------------- prep: w1t = transpose(scale_rows(w1, ln_g)) in bf16 ----------------
__global__ __launch_bounds__(256) void k_w1prep(const float* __restrict__ w1,
                                                const float* __restrict__ ln_g,
                                                char* __restrict__ ws) {
  __shared__ float tile[64][68];
  const int bx = blockIdx.x;
  const int e = bx >> 4, kt = (bx >> 2) & 3, nt = bx & 3;
  const int t = threadIdx.x;
  {
    const int r = t >> 2, cs = t & 3;
    const float* src = w1 + ((size_t)e * 256 + kt * 64 + r) * 256 + nt * 64 + cs * 16;
#pragma unroll
    for (int j = 0; j < 4; ++j) {
      float4 v = *(const float4*)(src + j * 4);
      *(float4*)(&tile[r][cs * 16 + j * 4]) = v;
    }
  }
  __syncthreads();
  {
    const int rn = t >> 2, ks = t & 3;
    bf16* dst = (bf16*)(ws + W1T_OFF) + (size_t)e * 65536 + (nt * 64 + rn) * 256 + kt * 64 + ks * 16;
#pragma unroll
    for (int j = 0; j < 4; ++j) {
      int kc = ks * 16 + j * 4;
      float4 g4 = *(const float4*)(ln_g + e * 256 + kt * 64 + kc);
      bf16x4 o;
      o[0] = (bf16)(tile[kc + 0][rn] * g4.x);
      o[1] = (bf16)(tile[kc + 1][rn] * g4.y);
      o[2] = (bf16)(tile[kc + 2][rn] * g4.z);
      o[3] = (bf16)(tile[kc + 3][rn] * g4.w);
      *(bf16x4*)(dst + j * 4) = o;
    }
  }
}

// ---------------- prep: w2t[e][c][h] (c padded to 16 with zeros), bf16 ----------------
__global__ __launch_bounds__(256) void k_w2prep(const float* __restrict__ w2,
                                                char* __restrict__ ws) {
  const int e = blockIdx.x, t = threadIdx.x;
  const int c = t >> 4, hs = t & 15;
  bf16* dst = (bf16*)(ws + W2T_OFF) + (size_t)e * 4096 + c * 256 + hs * 16;
#pragma unroll
  for (int j4 = 0; j4 < 4; ++j4) {
    bf16x4 o;
#pragma unroll
    for (int j = 0; j < 4; ++j) {
      int h = hs * 16 + j4 * 4 + j;
      float v = (c < 10) ? w2[((size_t)e * 256 + h) * 10 + c] : 0.0f;
      o[j] = (bf16)v;
    }
    *(bf16x4*)(dst + j4 * 4) = o;
  }
}

// ---------------- prep: b1p = b1 + ln_b @ w1 (fp32) ----------------
__global__ __launch_bounds__(256) void k_b1prep(const float* __restrict__ w1,
                                                const float* __restrict__ ln_b,
                                                const float* __restrict__ b1,
                                                char* __restrict__ ws) {
  __shared__ float part[4][64];
  const int e = blockIdx.x, nt = blockIdx.y;
  const int t = threadIdx.x;
  const int n = nt * 64 + (t & 63), q = t >> 6;
  float acc = 0.f;
#pragma unroll 8
  for (int i = 0; i < 64; ++i) {
    int k = q * 64 + i;
    acc += ln_b[e * 256 + k] * w1[((size_t)e * 256 + k) * 256 + n];
  }
  part[q][t & 63] = acc;
  __syncthreads();
  if (q == 0) {
    float s = part[0][t] + part[1][t] + part[2][t] + part[3][t] + b1[e * 256 + n];
    ((float*)(ws + B1P_OFF))[e * 256 + n] = s;
  }
}

// ---------------- LN stats + xhat(bf16) + router softmax + top-4 ----------------
__global__ __launch_bounds__(256) void k_ln_router(const float* __restrict__ feat,
                                                   const float* __restrict__ rw,
                                                   const float* __restrict__ rb,
                                                   float* __restrict__ out,
                                                   char* __restrict__ ws) {
  __shared__ float rwt[16][260];   // router_w transposed [e][d], padded
  __shared__ float xrow[4][256];
  const int t = threadIdx.x;
  const int w = t >> 6, l = t & 63;
  const int b = blockIdx.x * 4 + w;

  float4 x4 = *(const float4*)(feat + (size_t)b * 256 + l * 4);

  // stage transposed router weights (block-wide)
#pragma unroll
  for (int i = 0; i < 16; ++i) {
    int idx = t + 256 * i;
    rwt[idx & 15][idx >> 4] = rw[idx];
  }
  *(float4*)(&xrow[w][l * 4]) = x4;

  // LN stats (wave allreduce)
  float s = x4.x + x4.y + x4.z + x4.w;
  float s2 = x4.x * x4.x + x4.y * x4.y + x4.z * x4.z + x4.w * x4.w;
#pragma unroll
  for (int off = 1; off < 64; off <<= 1) {
    s += __shfl_xor(s, off);
    s2 += __shfl_xor(s2, off);
  }
  float mu = s * (1.0f / 256.0f);
  float var = s2 * (1.0f / 256.0f) - mu * mu;
  float rstd = __builtin_amdgcn_rsqf(var + 1e-5f);
  bf16x4 hb;
  hb[0] = (bf16)((x4.x - mu) * rstd);
  hb[1] = (bf16)((x4.y - mu) * rstd);
  hb[2] = (bf16)((x4.z - mu) * rstd);
  hb[3] = (bf16)((x4.w - mu) * rstd);
  *(bf16x4*)(ws + XHAT_OFF + ((size_t)b * 256 + l * 4) * 2) = hb;

  __syncthreads();

  // gate logits: lane owns expert e=l&15, quarter q=l>>4 of D
  const int e = l & 15, q = l >> 4;
  float g = 0.f;
#pragma unroll
  for (int i = 0; i < 16; ++i) {
    float4 xv = *(const float4*)(&xrow[w][q * 64 + i * 4]);
    float4 wv = *(const float4*)(&rwt[e][q * 64 + i * 4]);
    g += xv.x * wv.x + xv.y * wv.y + xv.z * wv.z + xv.w * wv.w;
  }
  g += __shfl_xor(g, 16);
  g += __shfl_xor(g, 32);
  g += rb[e];

  // softmax over 16 experts (within 16-lane groups, replicated)
  float m = g;
#pragma unroll
  for (int off = 1; off < 16; off <<= 1) m = fmaxf(m, __shfl_xor(m, off));
  float p = __builtin_amdgcn_exp2f((g - m) * LOG2E);
  float sum = p;
#pragma unroll
  for (int off = 1; off < 16; off <<= 1) sum += __shfl_xor(sum, off);
  float prob = p * __builtin_amdgcn_rcpf(sum);
  if (q == 0) out[GATE_OFF + (size_t)b * 16 + e] = prob;

  // top-4 (redundant on all lanes; uniform)
  float pv[16];
#pragma unroll
  for (int i = 0; i < 16; ++i) pv[i] = __shfl(prob, i);
  int idxk[4];
  float valk[4];
#pragma unroll
  for (int k = 0; k < 4; ++k) {
    float best = pv[0];
    int bi = 0;
#pragma unroll
    for (int i = 1; i < 16; ++i) {
      if (pv[i] > best) { best = pv[i]; bi = i; }
    }
    valk[k] = best;
    idxk[k] = bi;
#pragma unroll
    for (int i = 0; i < 16; ++i) pv[i] = (i == bi) ? -1.0f : pv[i];
  }
  float wsum = valk[0] + valk[1] + valk[2] + valk[3];
  float rn = __builtin_amdgcn_rcpf(wsum);
  if (l == 0) {
    int4 iv = {idxk[0], idxk[1], idxk[2], idxk[3]};
    float4 wv = {valk[0] * rn, valk[1] * rn, valk[2] * rn, valk[3] * rn};
    *(int4*)(ws + TKI_OFF + (size_t)b * 16) = iv;
    *(float4*)(ws + TKW_OFF + (size_t)b * 16) = wv;
  }
}

// ---------------- main fused: GEMM1(bf16 MFMA) -> GELU -> GEMM2 -> softmax -> all_probs ----------------
// grid (16 e, 256 mtiles), 512 threads (8 waves, 2x4 over 64x256 tile), BK=32, dbuf.
// LDS: Abuf 2x4096 @0 ; Bbuf 2x16384 @8192 ; h [64][264] bf16 @0 (reuse) ; w2 [16][512B] @40960
__global__ __launch_bounds__(512, 4) void k_moe(const char* __restrict__ ws,
                                                const float* __restrict__ b2g,
                                                float* __restrict__ out) {
  __shared__ __align__(16) char smem[49152];
  const int e = blockIdx.x;
  const int m0 = blockIdx.y * 64;
  const int t = threadIdx.x;
  const int wid = t >> 6, l = t & 63;
  const int lq = l >> 4, lr = l & 15;
  const int wr = wid >> 2, wc = wid & 3;

  const uint16_t* xhat = (const uint16_t*)(ws + XHAT_OFF);
  const uint16_t* w1t = (const uint16_t*)(ws + W1T_OFF) + (size_t)e * 65536;
  const uint16_t* w2t = (const uint16_t*)(ws + W2T_OFF) + (size_t)e * 4096;
  const float* b1p = (const float*)(ws + B1P_OFF) + e * 256;

  // stage w2t tile once (8KB, chunk-swizzled)
  {
    int n = t >> 5, ch = t & 31;
    const uint16_t* src = w2t + n * 256 + ((ch ^ (n & 15)) * 8);
    gl_lds16(src, smem + 40960 + wid * 1024);
  }

  auto stageAB = [&](int buf, int kt) {
    {  // B tile rows 0..127
      int n = t >> 2, ch = t & 3;
      const uint16_t* src = w1t + n * 256 + kt * 32 + ((ch ^ (n & 3)) * 8);
      gl_lds16(src, smem + 8192 + buf * 16384 + wid * 1024);
    }
    {  // B tile rows 128..255
      int s = t + 512;
      int n = s >> 2, ch = s & 3;
      const uint16_t* src = w1t + n * 256 + kt * 32 + ((ch ^ (n & 3)) * 8);
      gl_lds16(src, smem + 8192 + buf * 16384 + 8192 + wid * 1024);
    }
    if (t < 256) {  // A tile 64 rows
      int r = t >> 2, ch = t & 3;
      const uint16_t* src = xhat + (size_t)(m0 + r) * 256 + kt * 32 + ((ch ^ (r & 3)) * 8);
      gl_lds16(src, smem + buf * 4096 + wid * 1024);
    }
  };

  f32x4 zz = {0.f, 0.f, 0.f, 0.f};
  f32x4 acc[2][4] = {{zz, zz, zz, zz}, {zz, zz, zz, zz}};

  stageAB(0, 0);
  __syncthreads();
  for (int kt = 0; kt < 8; ++kt) {
    int buf = kt & 1;
    if (kt < 7) stageAB(buf ^ 1, kt + 1);
    bf16x8 a[2], bf[4];
#pragma unroll
    for (int mi = 0; mi < 2; ++mi) {
      int ra = wr * 32 + mi * 16 + lr;
      a[mi] = *(const bf16x8*)(smem + buf * 4096 + ra * 64 + ((lq ^ (ra & 3)) * 16));
    }
#pragma unroll
    for (int nj = 0; nj < 4; ++nj) {
      int rb_ = wc * 64 + nj * 16 + lr;
      bf[nj] = *(const bf16x8*)(smem + 8192 + buf * 16384 + rb_ * 64 + ((lq ^ (rb_ & 3)) * 16));
    }
#pragma unroll
    for (int mi = 0; mi < 2; ++mi)
#pragma unroll
      for (int nj = 0; nj < 4; ++nj)
        acc[mi][nj] = __builtin_amdgcn_mfma_f32_16x16x32_bf16(a[mi], bf[nj], acc[mi][nj], 0, 0, 0);
    __syncthreads();
  }

  // bias + GELU -> h in LDS (row-major [64][264] bf16, padded)
  float bc[4];
#pragma unroll
  for (int nj = 0; nj < 4; ++nj) bc[nj] = b1p[wc * 64 + nj * 16 + lr];
  bf16* hl = (bf16*)smem;
#pragma unroll
  for (int mi = 0; mi < 2; ++mi)
#pragma unroll
    for (int nj = 0; nj < 4; ++nj)
#pragma unroll
      for (int rg = 0; rg < 4; ++rg) {
        int row = wr * 32 + mi * 16 + lq * 4 + rg;
        int col = wc * 64 + nj * 16 + lr;
        hl[row * 264 + col] = (bf16)gelu_f(acc[mi][nj][rg] + bc[nj]);
      }
  __syncthreads();

  // GEMM2: waves 0..3, 16 rows each; K=256; N=16 (c padded)
  if (wid < 4) {
    f32x4 acc2 = {0.f, 0.f, 0.f, 0.f};
#pragma unroll
    for (int kk = 0; kk < 8; ++kk) {
      int rowa = wid * 16 + lr;
      bf16x8 a2 = *(const bf16x8*)(smem + rowa * 528 + lq * 16 + kk * 64);
      int chb = (lq + kk * 4) ^ lr;
      bf16x8 b2f = *(const bf16x8*)(smem + 40960 + lr * 512 + chb * 16);
      acc2 = __builtin_amdgcn_mfma_f32_16x16x32_bf16(a2, b2f, acc2, 0, 0, 0);
    }
    // row softmax over c (lanes 0..15 of each quarter), write all_probs
    const int c = lr;
    float bias2 = (c < 10) ? b2g[e * 10 + c] : 0.0f;
#pragma unroll
    for (int rg = 0; rg < 4; ++rg) {
      float logit = acc2[rg] + bias2;
      float v = (c < 10) ? logit : -3.0e38f;
      float mx = v;
#pragma unroll
      for (int off = 1; off < 16; off <<= 1) mx = fmaxf(mx, __shfl_xor(mx, off));
      float ex = (c < 10) ? __builtin_amdgcn_exp2f((logit - mx) * LOG2E) : 0.0f;
      float sm = ex;
#pragma unroll
      for (int off = 1; off < 16; off <<= 1) sm += __shfl_xor(sm, off);
      if (c < 10) {
        float pr = ex * __builtin_amdgcn_rcpf(sm);
        size_t row = (size_t)e * 16384 + (m0 + wid * 16 + lq * 4 + rg);
        out[APROBS_OFF + row * 10 + c] = pr;
      }
    }
  }
}

// ---------------- market_probs = sum_k w_k * all_probs[idx_k, b, :] ----------------
__global__ __launch_bounds__(256) void k_market(const char* __restrict__ ws,
                                                float* __restrict__ out) {
  const int b = blockIdx.x * 256 + threadIdx.x;
  int4 id = *(const int4*)(ws + TKI_OFF + (size_t)b * 16);
  float4 wv = *(const float4*)(ws + TKW_OFF + (size_t)b * 16);
  const int ids[4] = {id.x, id.y, id.z, id.w};
  const float wss[4] = {wv.x, wv.y, wv.z, wv.w};
  float m[10];
#pragma unroll
  for (int c = 0; c < 10; ++c) m[c] = 0.f;
#pragma unroll
  for (int k = 0; k < 4; ++k) {
    const float* ap = out + APROBS_OFF + ((size_t)ids[k] * 16384 + b) * 10;
#pragma unroll
    for (int c = 0; c < 10; ++c) m[c] += wss[k] * ap[c];
  }
#pragma unroll
  for (int c = 0; c < 10; ++c) out[(size_t)b * 10 + c] = m[c];
}

extern "C" void kernel_launch(void* const* d_in, const int* in_sizes, int n_in,
                              void* d_out, int out_size, void* d_ws, size_t ws_size,
                              hipStream_t stream) {
  (void)in_sizes; (void)n_in; (void)out_size; (void)ws_size;
  const float* feat = (const float*)d_in[0];
  const float* rw   = (const float*)d_in[1];
  const float* rb   = (const float*)d_in[2];
  const float* ln_g = (const float*)d_in[3];
  const float* ln_b = (const float*)d_in[4];
  const float* w1   = (const float*)d_in[5];
  const float* b1   = (const float*)d_in[6];
  const float* w2   = (const float*)d_in[7];
  const float* b2   = (const float*)d_in[8];
  float* out = (float*)d_out;
  char* ws = (char*)d_ws;

  hipLaunchKernelGGL(k_w1prep, dim3(256), dim3(256), 0, stream, w1, ln_g, ws);
  hipLaunchKernelGGL(k_w2prep, dim3(16), dim3(256), 0, stream, w2, ws);
  hipLaunchKernelGGL(k_b1prep, dim3(16, 4), dim3(256), 0, stream, w1, ln_b, b1, ws);
  hipLaunchKernelGGL(k_ln_router, dim3(4096), dim3(256), 0, stream, feat, rw, rb, out, ws);
  hipLaunchKernelGGL(k_moe, dim3(16, 256), dim3(512), 0, stream, ws, b2, out);
  hipLaunchKernelGGL(k_market, dim3(64), dim3(256), 0, stream, ws, out);
}

// Round 2
// 93.176 us; speedup vs baseline: 1.1607x; 1.1607x over previous
//
#include <hip/hip_runtime.h>
#include <hip/hip_bf16.h>
#include <stdint.h>

// Problem: B=16384, D=256, E=16, K=4, C=10
// out = [market_probs (B*C) | all_probs (E*B*C) | gate_probs (B*E)], fp32
// ws layout (bytes):
//   xhat bf16 [B][256]           @ 0        (8388608)
//   w1t  bf16 [E][256 n][256 k]  @ 8388608  (2097152)   w1t[e][n][k] = ln_g[e][k]*w1[e][k][n]
//   w2t  bf16 [E][16 c][256 h]   @ 10485760 (131072)    zero-padded c=10..15
//   b1p  f32  [E][256]           @ 10616832 (16384)     b1 + ln_b @ w1
//   tki  int  [B][4]             @ 10633216 (262144)
//   tkw  f32  [B][4]             @ 10895360 (262144)

typedef __bf16 bf16;
typedef __bf16 bf16x8 __attribute__((ext_vector_type(8)));
typedef __bf16 bf16x4 __attribute__((ext_vector_type(4)));
typedef float  f32x4  __attribute__((ext_vector_type(4)));

#define XHAT_OFF 0UL
#define W1T_OFF  8388608UL
#define W2T_OFF  10485760UL
#define B1P_OFF  10616832UL
#define TKI_OFF  10633216UL
#define TKW_OFF  10895360UL

#define APROBS_OFF 163840UL
#define GATE_OFF   2785280UL

#define LOG2E 1.4426950408889634f

__device__ __forceinline__ void gl_lds16(const void* g, void* l) {
  __builtin_amdgcn_global_load_lds((const __attribute__((address_space(1))) void*)g,
                                   (__attribute__((address_space(3))) void*)l, 16, 0, 0);
}

// tanh-approx GELU via exp2: max abs err vs exact (erf) gelu ~1e-3.
__device__ __forceinline__ float gelu_f(float x) {
  float s = x * x;
  float z = x * (2.3022082f + 0.10294324f * s);
  float t = __builtin_amdgcn_exp2f(z);
  float r = __builtin_amdgcn_rcpf(t + 1.0f);
  return x - x * r;
}

// ---------------- fused prep: w1t (256 blocks) | b1p (64) | w2t (16) ----------------
__global__ __launch_bounds__(256) void k_prep(const float* __restrict__ w1,
                                              const float* __restrict__ ln_g,
                                              const float* __restrict__ ln_b,
                                              const float* __restrict__ b1,
                                              const float* __restrict__ w2,
                                              char* __restrict__ ws) {
  __shared__ float tile[64][68];
  const int bid = blockIdx.x;
  const int t = threadIdx.x;

  if (bid < 256) {  // w1t = transpose(scale_rows(w1, ln_g)) in bf16
    const int e = bid >> 4, kt = (bid >> 2) & 3, nt = bid & 3;
    {
      const int r = t >> 2, cs = t & 3;
      const float* src = w1 + ((size_t)e * 256 + kt * 64 + r) * 256 + nt * 64 + cs * 16;
#pragma unroll
      for (int j = 0; j < 4; ++j) {
        float4 v = *(const float4*)(src + j * 4);
        *(float4*)(&tile[r][cs * 16 + j * 4]) = v;
      }
    }
    __syncthreads();
    {
      const int rn = t >> 2, ks = t & 3;
      bf16* dst = (bf16*)(ws + W1T_OFF) + (size_t)e * 65536 + (nt * 64 + rn) * 256 + kt * 64 + ks * 16;
#pragma unroll
      for (int j = 0; j < 4; ++j) {
        int kc = ks * 16 + j * 4;
        float4 g4 = *(const float4*)(ln_g + e * 256 + kt * 64 + kc);
        bf16x4 o;
        o[0] = (bf16)(tile[kc + 0][rn] * g4.x);
        o[1] = (bf16)(tile[kc + 1][rn] * g4.y);
        o[2] = (bf16)(tile[kc + 2][rn] * g4.z);
        o[3] = (bf16)(tile[kc + 3][rn] * g4.w);
        *(bf16x4*)(dst + j * 4) = o;
      }
    }
  } else if (bid < 320) {  // b1p = b1 + ln_b @ w1
    const int b2i = bid - 256;
    const int e = b2i & 15, nt = b2i >> 4;
    const int n = nt * 64 + (t & 63), q = t >> 6;
    float acc = 0.f;
#pragma unroll 8
    for (int i = 0; i < 64; ++i) {
      int k = q * 64 + i;
      acc += ln_b[e * 256 + k] * w1[((size_t)e * 256 + k) * 256 + n];
    }
    float* part = (float*)tile;
    part[q * 64 + (t & 63)] = acc;
    __syncthreads();
    if (q == 0) {
      float s = part[t] + part[64 + t] + part[128 + t] + part[192 + t] + b1[e * 256 + n];
      ((float*)(ws + B1P_OFF))[e * 256 + n] = s;
    }
  } else {  // w2t[e][c][h], c padded to 16
    const int e = bid - 320;
    const int c = t >> 4, hs = t & 15;
    bf16* dst = (bf16*)(ws + W2T_OFF) + (size_t)e * 4096 + c * 256 + hs * 16;
#pragma unroll
    for (int j4 = 0; j4 < 4; ++j4) {
      bf16x4 o;
#pragma unroll
      for (int j = 0; j < 4; ++j) {
        int h = hs * 16 + j4 * 4 + j;
        float v = (c < 10) ? w2[((size_t)e * 256 + h) * 10 + c] : 0.0f;
        o[j] = (bf16)v;
      }
      *(bf16x4*)(dst + j4 * 4) = o;
    }
  }
}

// ---------------- LN stats + xhat(bf16) + router softmax + top-4 ----------------
__global__ __launch_bounds__(256) void k_ln_router(const float* __restrict__ feat,
                                                   const float* __restrict__ rw,
                                                   const float* __restrict__ rb,
                                                   float* __restrict__ out,
                                                   char* __restrict__ ws) {
  __shared__ float rwt[16][260];
  __shared__ float xrow[4][256];
  const int t = threadIdx.x;
  const int w = t >> 6, l = t & 63;
  const int b = blockIdx.x * 4 + w;

  float4 x4 = *(const float4*)(feat + (size_t)b * 256 + l * 4);

#pragma unroll
  for (int i = 0; i < 16; ++i) {
    int idx = t + 256 * i;
    rwt[idx & 15][idx >> 4] = rw[idx];
  }
  *(float4*)(&xrow[w][l * 4]) = x4;

  float s = x4.x + x4.y + x4.z + x4.w;
  float s2 = x4.x * x4.x + x4.y * x4.y + x4.z * x4.z + x4.w * x4.w;
#pragma unroll
  for (int off = 1; off < 64; off <<= 1) {
    s += __shfl_xor(s, off);
    s2 += __shfl_xor(s2, off);
  }
  float mu = s * (1.0f / 256.0f);
  float var = s2 * (1.0f / 256.0f) - mu * mu;
  float rstd = __builtin_amdgcn_rsqf(var + 1e-5f);
  bf16x4 hb;
  hb[0] = (bf16)((x4.x - mu) * rstd);
  hb[1] = (bf16)((x4.y - mu) * rstd);
  hb[2] = (bf16)((x4.z - mu) * rstd);
  hb[3] = (bf16)((x4.w - mu) * rstd);
  *(bf16x4*)(ws + XHAT_OFF + ((size_t)b * 256 + l * 4) * 2) = hb;

  __syncthreads();

  const int e = l & 15, q = l >> 4;
  float g = 0.f;
#pragma unroll
  for (int i = 0; i < 16; ++i) {
    float4 xv = *(const float4*)(&xrow[w][q * 64 + i * 4]);
    float4 wv = *(const float4*)(&rwt[e][q * 64 + i * 4]);
    g += xv.x * wv.x + xv.y * wv.y + xv.z * wv.z + xv.w * wv.w;
  }
  g += __shfl_xor(g, 16);
  g += __shfl_xor(g, 32);
  g += rb[e];

  float m = g;
#pragma unroll
  for (int off = 1; off < 16; off <<= 1) m = fmaxf(m, __shfl_xor(m, off));
  float p = __builtin_amdgcn_exp2f((g - m) * LOG2E);
  float sum = p;
#pragma unroll
  for (int off = 1; off < 16; off <<= 1) sum += __shfl_xor(sum, off);
  float prob = p * __builtin_amdgcn_rcpf(sum);
  if (q == 0) out[GATE_OFF + (size_t)b * 16 + e] = prob;

  float pv[16];
#pragma unroll
  for (int i = 0; i < 16; ++i) pv[i] = __shfl(prob, i);
  int idxk[4];
  float valk[4];
#pragma unroll
  for (int k = 0; k < 4; ++k) {
    float best = pv[0];
    int bi = 0;
#pragma unroll
    for (int i = 1; i < 16; ++i) {
      if (pv[i] > best) { best = pv[i]; bi = i; }
    }
    valk[k] = best;
    idxk[k] = bi;
#pragma unroll
    for (int i = 0; i < 16; ++i) pv[i] = (i == bi) ? -1.0f : pv[i];
  }
  float wsum = valk[0] + valk[1] + valk[2] + valk[3];
  float rn = __builtin_amdgcn_rcpf(wsum);
  if (l == 0) {
    int4 iv = {idxk[0], idxk[1], idxk[2], idxk[3]};
    float4 wv = {valk[0] * rn, valk[1] * rn, valk[2] * rn, valk[3] * rn};
    *(int4*)(ws + TKI_OFF + (size_t)b * 16) = iv;
    *(float4*)(ws + TKW_OFF + (size_t)b * 16) = wv;
  }
}

// ---------------- main fused: GEMM1(bf16 MFMA) -> GELU -> GEMM2 -> softmax -> all_probs
// grid (256 mtiles, 16 e), 512 threads (8 waves 2m x 4n over 64x256), BK=64,
// single-buffer + reg-prefetch 2-phase; 128 B LDS rows with chunk^(row&7) XOR swizzle.
// LDS: A [64][128B] @0 ; B [256][128B] @8192 ; w2 [16][512B] @40960 ; h [64][528B] @0 (reuse)
__global__ __launch_bounds__(512, 4) void k_moe(const char* __restrict__ ws,
                                                const float* __restrict__ b2g,
                                                float* __restrict__ out) {
  __shared__ __align__(16) char smem[49152];
  const int m0 = blockIdx.x * 64;
  const int e = blockIdx.y;
  const int t = threadIdx.x;
  const int wid = t >> 6, l = t & 63;
  const int lq = l >> 4, lr = l & 15;
  const int wr = wid >> 2, wc = wid & 3;

  const uint16_t* xhat = (const uint16_t*)(ws + XHAT_OFF);
  const uint16_t* w1t = (const uint16_t*)(ws + W1T_OFF) + (size_t)e * 65536;
  const uint16_t* w2t = (const uint16_t*)(ws + W2T_OFF) + (size_t)e * 4096;
  const float* b1p = (const float*)(ws + B1P_OFF) + e * 256;

  // hoisted stage sources (pre-swizzled: dest slot c holds src chunk c^(row&7))
  const int tr = t >> 3, tc = t & 7;
  const uint16_t* sA = xhat + (size_t)(m0 + tr) * 256 + (tc ^ (tr & 7)) * 8;
  const uint16_t* sB = w1t + tr * 256 + (tc ^ (tr & 7)) * 8;
  const uint16_t* sW = w2t + (t >> 5) * 256 + ((t & 31) ^ ((t >> 5) & 7)) * 8;
  char* dA = smem + wid * 1024;
  char* dB = smem + 8192 + wid * 1024;
  char* dW = smem + 40960 + wid * 1024;

  gl_lds16(sW, dW);
  gl_lds16(sA, dA);
  gl_lds16(sB, dB);
  gl_lds16(sB + 16384, dB + 8192);
  gl_lds16(sB + 32768, dB + 16384);
  gl_lds16(sB + 49152, dB + 24576);

  // hoisted fragment LDS byte offsets (single buffer -> loop-invariant)
  int aoff[2][2], boff[4][2];
#pragma unroll
  for (int mi = 0; mi < 2; ++mi) {
    int ra = wr * 32 + mi * 16 + lr;
#pragma unroll
    for (int kk = 0; kk < 2; ++kk)
      aoff[mi][kk] = ra * 128 + (((4 * kk + lq) ^ (ra & 7)) << 4);
  }
#pragma unroll
  for (int nj = 0; nj < 4; ++nj) {
    int rb_ = wc * 64 + nj * 16 + lr;
#pragma unroll
    for (int kk = 0; kk < 2; ++kk)
      boff[nj][kk] = 8192 + rb_ * 128 + (((4 * kk + lq) ^ (rb_ & 7)) << 4);
  }

  f32x4 zz = {0.f, 0.f, 0.f, 0.f};
  f32x4 acc[2][4] = {{zz, zz, zz, zz}, {zz, zz, zz, zz}};

  __syncthreads();
#pragma unroll
  for (int kt = 0; kt < 4; ++kt) {
    bf16x8 af[2][2], bfr[4][2];
#pragma unroll
    for (int mi = 0; mi < 2; ++mi)
#pragma unroll
      for (int kk = 0; kk < 2; ++kk)
        af[mi][kk] = *(const bf16x8*)(smem + aoff[mi][kk]);
#pragma unroll
    for (int nj = 0; nj < 4; ++nj)
#pragma unroll
      for (int kk = 0; kk < 2; ++kk)
        bfr[nj][kk] = *(const bf16x8*)(smem + boff[nj][kk]);
    __syncthreads();  // all waves captured frags; safe to overwrite
    if (kt < 3) {
      const uint16_t* a = sA + (kt + 1) * 64;
      const uint16_t* b = sB + (kt + 1) * 64;
      gl_lds16(a, dA);
      gl_lds16(b, dB);
      gl_lds16(b + 16384, dB + 8192);
      gl_lds16(b + 32768, dB + 16384);
      gl_lds16(b + 49152, dB + 24576);
    }
#pragma unroll
    for (int kk = 0; kk < 2; ++kk)
#pragma unroll
      for (int mi = 0; mi < 2; ++mi)
#pragma unroll
        for (int nj = 0; nj < 4; ++nj)
          acc[mi][nj] = __builtin_amdgcn_mfma_f32_16x16x32_bf16(af[mi][kk], bfr[nj][kk], acc[mi][nj], 0, 0, 0);
    if (kt < 3) __syncthreads();  // staged tile landed
  }

  // bias + GELU -> h in LDS ([64][264] bf16 rows = 528 B)
  float bc[4];
#pragma unroll
  for (int nj = 0; nj < 4; ++nj) bc[nj] = b1p[wc * 64 + nj * 16 + lr];
  bf16* hl = (bf16*)smem;
#pragma unroll
  for (int mi = 0; mi < 2; ++mi)
#pragma unroll
    for (int nj = 0; nj < 4; ++nj)
#pragma unroll
      for (int rg = 0; rg < 4; ++rg) {
        int row = wr * 32 + mi * 16 + lq * 4 + rg;
        int col = wc * 64 + nj * 16 + lr;
        hl[row * 264 + col] = (bf16)gelu_f(acc[mi][nj][rg] + bc[nj]);
      }
  __syncthreads();

  // GEMM2: waves 0..3, 16 rows each; K=256; N=16 (c padded)
  if (wid < 4) {
    f32x4 acc2 = {0.f, 0.f, 0.f, 0.f};
    const int rowa = wid * 16 + lr;
#pragma unroll
    for (int kk = 0; kk < 8; ++kk) {
      bf16x8 a2 = *(const bf16x8*)(smem + rowa * 528 + lq * 16 + kk * 64);
      bf16x8 b2f = *(const bf16x8*)(smem + 40960 + lr * 512 + (((lq + 4 * kk) ^ (lr & 7)) << 4));
      acc2 = __builtin_amdgcn_mfma_f32_16x16x32_bf16(a2, b2f, acc2, 0, 0, 0);
    }
    const int c = lr;
    float bias2 = (c < 10) ? b2g[e * 10 + c] : 0.0f;
#pragma unroll
    for (int rg = 0; rg < 4; ++rg) {
      float logit = acc2[rg] + bias2;
      float v = (c < 10) ? logit : -3.0e38f;
      float mx = v;
#pragma unroll
      for (int off = 1; off < 16; off <<= 1) mx = fmaxf(mx, __shfl_xor(mx, off));
      float ex = (c < 10) ? __builtin_amdgcn_exp2f((logit - mx) * LOG2E) : 0.0f;
      float sm = ex;
#pragma unroll
      for (int off = 1; off < 16; off <<= 1) sm += __shfl_xor(sm, off);
      if (c < 10) {
        float pr = ex * __builtin_amdgcn_rcpf(sm);
        size_t row = (size_t)e * 16384 + (m0 + wid * 16 + lq * 4 + rg);
        out[APROBS_OFF + row * 10 + c] = pr;
      }
    }
  }
}

// ---------------- market_probs = sum_k w_k * all_probs[idx_k, b, :] ----------------
__global__ __launch_bounds__(256) void k_market(const char* __restrict__ ws,
                                                float* __restrict__ out) {
  const int b = blockIdx.x * 256 + threadIdx.x;
  int4 id = *(const int4*)(ws + TKI_OFF + (size_t)b * 16);
  float4 wv = *(const float4*)(ws + TKW_OFF + (size_t)b * 16);
  const int ids[4] = {id.x, id.y, id.z, id.w};
  const float wss[4] = {wv.x, wv.y, wv.z, wv.w};
  float m[10];
#pragma unroll
  for (int c = 0; c < 10; ++c) m[c] = 0.f;
#pragma unroll
  for (int k = 0; k < 4; ++k) {
    const float* ap = out + APROBS_OFF + ((size_t)ids[k] * 16384 + b) * 10;
#pragma unroll
    for (int c = 0; c < 10; ++c) m[c] += wss[k] * ap[c];
  }
#pragma unroll
  for (int c = 0; c < 10; ++c) out[(size_t)b * 10 + c] = m[c];
}

extern "C" void kernel_launch(void* const* d_in, const int* in_sizes, int n_in,
                              void* d_out, int out_size, void* d_ws, size_t ws_size,
                              hipStream_t stream) {
  (void)in_sizes; (void)n_in; (void)out_size; (void)ws_size;
  const float* feat = (const float*)d_in[0];
  const float* rw   = (const float*)d_in[1];
  const float* rb   = (const float*)d_in[2];
  const float* ln_g = (const float*)d_in[3];
  const float* ln_b = (const float*)d_in[4];
  const float* w1   = (const float*)d_in[5];
  const float* b1   = (const float*)d_in[6];
  const float* w2   = (const float*)d_in[7];
  const float* b2   = (const float*)d_in[8];
  float* out = (float*)d_out;
  char* ws = (char*)d_ws;

  hipLaunchKernelGGL(k_prep, dim3(336), dim3(256), 0, stream, w1, ln_g, ln_b, b1, w2, ws);
  hipLaunchKernelGGL(k_ln_router, dim3(4096), dim3(256), 0, stream, feat, rw, rb, out, ws);
  hipLaunchKernelGGL(k_moe, dim3(256, 16), dim3(512), 0, stream, ws, b2, out);
  hipLaunchKernelGGL(k_market, dim3(64), dim3(256), 0, stream, ws, out);
}

// Round 3
// 88.594 us; speedup vs baseline: 1.2208x; 1.0517x over previous
//
#include <hip/hip_runtime.h>
#include <hip/hip_bf16.h>
#include <stdint.h>

// Problem: B=16384, D=256, E=16, K=4, C=10
// out = [market_probs (B*C) | all_probs (E*B*C) | gate_probs (B*E)], fp32
// ws layout (bytes):
//   xhat bf16 [B][256]           @ 0        (8388608)
//   w1t  bf16 [E][256 n][256 k]  @ 8388608  (2097152)   w1t[e][n][k] = ln_g[e][k]*w1[e][k][n]
//   w2t  bf16 [E][16 c][256 h]   @ 10485760 (131072)    zero-padded c=10..15
//   b1p  f32  [E][256]           @ 10616832 (16384)     b1 + ln_b @ w1
//   tki  int  [B][4]             @ 10633216 (262144)
//   tkw  f32  [B][4]             @ 10895360 (262144)

typedef __bf16 bf16;
typedef __bf16 bf16x8 __attribute__((ext_vector_type(8)));
typedef __bf16 bf16x4 __attribute__((ext_vector_type(4)));
typedef float  f32x4  __attribute__((ext_vector_type(4)));

#define XHAT_OFF 0UL
#define W1T_OFF  8388608UL
#define W2T_OFF  10485760UL
#define B1P_OFF  10616832UL
#define TKI_OFF  10633216UL
#define TKW_OFF  10895360UL

#define APROBS_OFF 163840UL
#define GATE_OFF   2785280UL

#define LOG2E 1.4426950408889634f

__device__ __forceinline__ void gl_lds16(const void* g, void* l) {
  __builtin_amdgcn_global_load_lds((const __attribute__((address_space(1))) void*)g,
                                   (__attribute__((address_space(3))) void*)l, 16, 0, 0);
}

// tanh-approx GELU via exp2: max abs err vs exact (erf) gelu ~1e-3.
__device__ __forceinline__ float gelu_f(float x) {
  float s = x * x;
  float z = x * (2.3022082f + 0.10294324f * s);
  float t = __builtin_amdgcn_exp2f(z);
  float r = __builtin_amdgcn_rcpf(t + 1.0f);
  return x - x * r;
}

// ---------------- fused prep: w1t (256 blocks) | b1p (64) | w2t (16) ----------------
__global__ __launch_bounds__(256) void k_prep(const float* __restrict__ w1,
                                              const float* __restrict__ ln_g,
                                              const float* __restrict__ ln_b,
                                              const float* __restrict__ b1,
                                              const float* __restrict__ w2,
                                              char* __restrict__ ws) {
  __shared__ float tile[64][68];
  const int bid = blockIdx.x;
  const int t = threadIdx.x;

  if (bid < 256) {  // w1t = transpose(scale_rows(w1, ln_g)) in bf16
    const int e = bid >> 4, kt = (bid >> 2) & 3, nt = bid & 3;
    {
      const int r = t >> 2, cs = t & 3;
      const float* src = w1 + ((size_t)e * 256 + kt * 64 + r) * 256 + nt * 64 + cs * 16;
#pragma unroll
      for (int j = 0; j < 4; ++j) {
        float4 v = *(const float4*)(src + j * 4);
        *(float4*)(&tile[r][cs * 16 + j * 4]) = v;
      }
    }
    __syncthreads();
    {
      const int rn = t >> 2, ks = t & 3;
      bf16* dst = (bf16*)(ws + W1T_OFF) + (size_t)e * 65536 + (nt * 64 + rn) * 256 + kt * 64 + ks * 16;
#pragma unroll
      for (int j = 0; j < 4; ++j) {
        int kc = ks * 16 + j * 4;
        float4 g4 = *(const float4*)(ln_g + e * 256 + kt * 64 + kc);
        bf16x4 o;
        o[0] = (bf16)(tile[kc + 0][rn] * g4.x);
        o[1] = (bf16)(tile[kc + 1][rn] * g4.y);
        o[2] = (bf16)(tile[kc + 2][rn] * g4.z);
        o[3] = (bf16)(tile[kc + 3][rn] * g4.w);
        *(bf16x4*)(dst + j * 4) = o;
      }
    }
  } else if (bid < 320) {  // b1p = b1 + ln_b @ w1
    const int b2i = bid - 256;
    const int e = b2i & 15, nt = b2i >> 4;
    const int n = nt * 64 + (t & 63), q = t >> 6;
    float acc = 0.f;
#pragma unroll 8
    for (int i = 0; i < 64; ++i) {
      int k = q * 64 + i;
      acc += ln_b[e * 256 + k] * w1[((size_t)e * 256 + k) * 256 + n];
    }
    float* part = (float*)tile;
    part[q * 64 + (t & 63)] = acc;
    __syncthreads();
    if (q == 0) {
      float s = part[t] + part[64 + t] + part[128 + t] + part[192 + t] + b1[e * 256 + n];
      ((float*)(ws + B1P_OFF))[e * 256 + n] = s;
    }
  } else {  // w2t[e][c][h], c padded to 16
    const int e = bid - 320;
    const int c = t >> 4, hs = t & 15;
    bf16* dst = (bf16*)(ws + W2T_OFF) + (size_t)e * 4096 + c * 256 + hs * 16;
#pragma unroll
    for (int j4 = 0; j4 < 4; ++j4) {
      bf16x4 o;
#pragma unroll
      for (int j = 0; j < 4; ++j) {
        int h = hs * 16 + j4 * 4 + j;
        float v = (c < 10) ? w2[((size_t)e * 256 + h) * 10 + c] : 0.0f;
        o[j] = (bf16)v;
      }
      *(bf16x4*)(dst + j4 * 4) = o;
    }
  }
}

// ---------------- LN stats + xhat(bf16) + router softmax + top-4 ----------------
__global__ __launch_bounds__(256) void k_ln_router(const float* __restrict__ feat,
                                                   const float* __restrict__ rw,
                                                   const float* __restrict__ rb,
                                                   float* __restrict__ out,
                                                   char* __restrict__ ws) {
  __shared__ float rwt[16][260];
  __shared__ float xrow[4][256];
  const int t = threadIdx.x;
  const int w = t >> 6, l = t & 63;
  const int b = blockIdx.x * 4 + w;

  float4 x4 = *(const float4*)(feat + (size_t)b * 256 + l * 4);

#pragma unroll
  for (int i = 0; i < 16; ++i) {
    int idx = t + 256 * i;
    rwt[idx & 15][idx >> 4] = rw[idx];
  }
  *(float4*)(&xrow[w][l * 4]) = x4;

  float s = x4.x + x4.y + x4.z + x4.w;
  float s2 = x4.x * x4.x + x4.y * x4.y + x4.z * x4.z + x4.w * x4.w;
#pragma unroll
  for (int off = 1; off < 64; off <<= 1) {
    s += __shfl_xor(s, off);
    s2 += __shfl_xor(s2, off);
  }
  float mu = s * (1.0f / 256.0f);
  float var = s2 * (1.0f / 256.0f) - mu * mu;
  float rstd = __builtin_amdgcn_rsqf(var + 1e-5f);
  bf16x4 hb;
  hb[0] = (bf16)((x4.x - mu) * rstd);
  hb[1] = (bf16)((x4.y - mu) * rstd);
  hb[2] = (bf16)((x4.z - mu) * rstd);
  hb[3] = (bf16)((x4.w - mu) * rstd);
  *(bf16x4*)(ws + XHAT_OFF + ((size_t)b * 256 + l * 4) * 2) = hb;

  __syncthreads();

  const int e = l & 15, q = l >> 4;
  float g = 0.f;
#pragma unroll
  for (int i = 0; i < 16; ++i) {
    float4 xv = *(const float4*)(&xrow[w][q * 64 + i * 4]);
    float4 wv = *(const float4*)(&rwt[e][q * 64 + i * 4]);
    g += xv.x * wv.x + xv.y * wv.y + xv.z * wv.z + xv.w * wv.w;
  }
  g += __shfl_xor(g, 16);
  g += __shfl_xor(g, 32);
  g += rb[e];

  float m = g;
#pragma unroll
  for (int off = 1; off < 16; off <<= 1) m = fmaxf(m, __shfl_xor(m, off));
  float p = __builtin_amdgcn_exp2f((g - m) * LOG2E);
  float sum = p;
#pragma unroll
  for (int off = 1; off < 16; off <<= 1) sum += __shfl_xor(sum, off);
  float prob = p * __builtin_amdgcn_rcpf(sum);
  if (q == 0) out[GATE_OFF + (size_t)b * 16 + e] = prob;

  float pv[16];
#pragma unroll
  for (int i = 0; i < 16; ++i) pv[i] = __shfl(prob, i);
  int idxk[4];
  float valk[4];
#pragma unroll
  for (int k = 0; k < 4; ++k) {
    float best = pv[0];
    int bi = 0;
#pragma unroll
    for (int i = 1; i < 16; ++i) {
      if (pv[i] > best) { best = pv[i]; bi = i; }
    }
    valk[k] = best;
    idxk[k] = bi;
#pragma unroll
    for (int i = 0; i < 16; ++i) pv[i] = (i == bi) ? -1.0f : pv[i];
  }
  float wsum = valk[0] + valk[1] + valk[2] + valk[3];
  float rn = __builtin_amdgcn_rcpf(wsum);
  if (l == 0) {
    int4 iv = {idxk[0], idxk[1], idxk[2], idxk[3]};
    float4 wv = {valk[0] * rn, valk[1] * rn, valk[2] * rn, valk[3] * rn};
    *(int4*)(ws + TKI_OFF + (size_t)b * 16) = iv;
    *(float4*)(ws + TKW_OFF + (size_t)b * 16) = wv;
  }
}

// ---------------- main fused: GEMM1(bf16 MFMA) -> GELU -> GEMM2 -> softmax -> all_probs
// BM=128, BN=256, BK=64; 2048 blocks (XCD-chunked, expert-fast), 512 threads
// (8 waves 2m x 4n, wave tile 64x64), single-buffer 2-phase, chunk^(row&7) swizzle.
// LDS: A[128][128B] @0 ; B[256][128B] @16384 ; h[128][528B] @0 (overlay) ; w2 @67584. Total 75776.
__global__ __launch_bounds__(512, 4) void k_moe(const char* __restrict__ ws,
                                                const float* __restrict__ b2g,
                                                float* __restrict__ out) {
  __shared__ __align__(16) char smem[75776];
  const int lin = blockIdx.x;
  const int e = (lin >> 3) & 15;                 // expert-fast within an XCD chunk
  const int mt = (lin & 7) * 16 + (lin >> 7);    // each XCD owns 16 contiguous mtiles
  const int m0 = mt * 128;
  const int t = threadIdx.x;
  const int wid = t >> 6, l = t & 63;
  const int lq = l >> 4, lr = l & 15;
  const int wr = wid >> 2, wc = wid & 3;

  const uint16_t* xhat = (const uint16_t*)(ws + XHAT_OFF);
  const uint16_t* w1t = (const uint16_t*)(ws + W1T_OFF) + (size_t)e * 65536;
  const uint16_t* w2t = (const uint16_t*)(ws + W2T_OFF) + (size_t)e * 4096;
  const float* b1p = (const float*)(ws + B1P_OFF) + e * 256;

  // stage sources (pre-swizzled: dest slot c holds src chunk c^(row&7))
  const int tr = t >> 3, tc = t & 7;
  const uint16_t* sA = xhat + (size_t)(m0 + tr) * 256 + (tc ^ (tr & 7)) * 8;
  const uint16_t* sB = w1t + tr * 256 + (tc ^ (tr & 7)) * 8;
  const uint16_t* sW = w2t + (t >> 5) * 256 + ((t & 31) ^ ((t >> 5) & 7)) * 8;
  char* dP = smem + wid * 1024;  // per-wave linear dest base

  gl_lds16(sW, dP + 67584);
  gl_lds16(sA, dP);
  gl_lds16(sA + 16384, dP + 8192);
  gl_lds16(sB, dP + 16384);
  gl_lds16(sB + 16384, dP + 24576);
  gl_lds16(sB + 32768, dP + 32768);
  gl_lds16(sB + 49152, dP + 40960);

  // fragment LDS byte offsets: row&7 == lr&7 for ALL fragments ->
  // swizzle term depends only on kk; per-frag deltas are compile-time imms.
  const int el = lr & 7;
  int aoff[2], boff[2];
#pragma unroll
  for (int kk = 0; kk < 2; ++kk) {
    int swz = ((4 * kk + lq) ^ el) << 4;
    aoff[kk] = (wr * 64 + lr) * 128 + swz;
    boff[kk] = 16384 + (wc * 64 + lr) * 128 + swz;
  }

  f32x4 zz = {0.f, 0.f, 0.f, 0.f};
  f32x4 acc[4][4];
#pragma unroll
  for (int mi = 0; mi < 4; ++mi)
#pragma unroll
    for (int nj = 0; nj < 4; ++nj) acc[mi][nj] = zz;

  __syncthreads();
#pragma unroll
  for (int kt = 0; kt < 4; ++kt) {
    bf16x8 af[4][2], bfr[4][2];
#pragma unroll
    for (int kk = 0; kk < 2; ++kk) {
#pragma unroll
      for (int mi = 0; mi < 4; ++mi)
        af[mi][kk] = *(const bf16x8*)(smem + aoff[kk] + mi * 2048);
#pragma unroll
      for (int nj = 0; nj < 4; ++nj)
        bfr[nj][kk] = *(const bf16x8*)(smem + boff[kk] + nj * 2048);
    }
    __syncthreads();  // all waves captured frags; safe to overwrite
    if (kt < 3) {
      const uint16_t* a = sA + (kt + 1) * 64;
      const uint16_t* b = sB + (kt + 1) * 64;
      gl_lds16(a, dP);
      gl_lds16(a + 16384, dP + 8192);
      gl_lds16(b, dP + 16384);
      gl_lds16(b + 16384, dP + 24576);
      gl_lds16(b + 32768, dP + 32768);
      gl_lds16(b + 49152, dP + 40960);
    }
#pragma unroll
    for (int kk = 0; kk < 2; ++kk)
#pragma unroll
      for (int mi = 0; mi < 4; ++mi)
#pragma unroll
        for (int nj = 0; nj < 4; ++nj)
          acc[mi][nj] = __builtin_amdgcn_mfma_f32_16x16x32_bf16(af[mi][kk], bfr[nj][kk], acc[mi][nj], 0, 0, 0);
    if (kt < 3) __syncthreads();  // staged tile landed
  }

  // bias + GELU -> h in LDS ([128][264] bf16 rows = 528 B), overlays A/B
  float bc[4];
#pragma unroll
  for (int nj = 0; nj < 4; ++nj) bc[nj] = b1p[wc * 64 + nj * 16 + lr];
  bf16* hl = (bf16*)smem;
#pragma unroll
  for (int mi = 0; mi < 4; ++mi)
#pragma unroll
    for (int nj = 0; nj < 4; ++nj)
#pragma unroll
      for (int rg = 0; rg < 4; ++rg) {
        int row = wr * 64 + mi * 16 + lq * 4 + rg;
        int col = wc * 64 + nj * 16 + lr;
        hl[row * 264 + col] = (bf16)gelu_f(acc[mi][nj][rg] + bc[nj]);
      }
  __syncthreads();

  // GEMM2: all 8 waves, 16 rows each; K=256; N=16 (c padded)
  {
    f32x4 acc2 = {0.f, 0.f, 0.f, 0.f};
    const int rowa = wid * 16 + lr;
#pragma unroll
    for (int kk = 0; kk < 8; ++kk) {
      bf16x8 a2 = *(const bf16x8*)(smem + rowa * 528 + lq * 16 + kk * 64);
      bf16x8 b2f = *(const bf16x8*)(smem + 67584 + lr * 512 + (((lq + 4 * kk) ^ el) << 4));
      acc2 = __builtin_amdgcn_mfma_f32_16x16x32_bf16(a2, b2f, acc2, 0, 0, 0);
    }
    const int c = lr;
    float bias2 = (c < 10) ? b2g[e * 10 + c] : 0.0f;
#pragma unroll
    for (int rg = 0; rg < 4; ++rg) {
      float logit = acc2[rg] + bias2;
      float v = (c < 10) ? logit : -3.0e38f;
      float mx = v;
#pragma unroll
      for (int off = 1; off < 16; off <<= 1) mx = fmaxf(mx, __shfl_xor(mx, off));
      float ex = (c < 10) ? __builtin_amdgcn_exp2f((logit - mx) * LOG2E) : 0.0f;
      float sm = ex;
#pragma unroll
      for (int off = 1; off < 16; off <<= 1) sm += __shfl_xor(sm, off);
      if (c < 10) {
        float pr = ex * __builtin_amdgcn_rcpf(sm);
        size_t row = (size_t)e * 16384 + (m0 + wid * 16 + lq * 4 + rg);
        out[APROBS_OFF + row * 10 + c] = pr;
      }
    }
  }
}

// ---------------- market_probs = sum_k w_k * all_probs[idx_k, b, :] ----------------
__global__ __launch_bounds__(256) void k_market(const char* __restrict__ ws,
                                                float* __restrict__ out) {
  const int b = blockIdx.x * 256 + threadIdx.x;
  int4 id = *(const int4*)(ws + TKI_OFF + (size_t)b * 16);
  float4 wv = *(const float4*)(ws + TKW_OFF + (size_t)b * 16);
  const int ids[4] = {id.x, id.y, id.z, id.w};
  const float wss[4] = {wv.x, wv.y, wv.z, wv.w};
  float m[10];
#pragma unroll
  for (int c = 0; c < 10; ++c) m[c] = 0.f;
#pragma unroll
  for (int k = 0; k < 4; ++k) {
    const float* ap = out + APROBS_OFF + ((size_t)ids[k] * 16384 + b) * 10;
#pragma unroll
    for (int c = 0; c < 10; ++c) m[c] += wss[k] * ap[c];
  }
#pragma unroll
  for (int c = 0; c < 10; ++c) out[(size_t)b * 10 + c] = m[c];
}

extern "C" void kernel_launch(void* const* d_in, const int* in_sizes, int n_in,
                              void* d_out, int out_size, void* d_ws, size_t ws_size,
                              hipStream_t stream) {
  (void)in_sizes; (void)n_in; (void)out_size; (void)ws_size;
  const float* feat = (const float*)d_in[0];
  const float* rw   = (const float*)d_in[1];
  const float* rb   = (const float*)d_in[2];
  const float* ln_g = (const float*)d_in[3];
  const float* ln_b = (const float*)d_in[4];
  const float* w1   = (const float*)d_in[5];
  const float* b1   = (const float*)d_in[6];
  const float* w2   = (const float*)d_in[7];
  const float* b2   = (const float*)d_in[8];
  float* out = (float*)d_out;
  char* ws = (char*)d_ws;

  hipLaunchKernelGGL(k_prep, dim3(336), dim3(256), 0, stream, w1, ln_g, ln_b, b1, w2, ws);
  hipLaunchKernelGGL(k_ln_router, dim3(4096), dim3(256), 0, stream, feat, rw, rb, out, ws);
  hipLaunchKernelGGL(k_moe, dim3(2048), dim3(512), 0, stream, ws, b2, out);
  hipLaunchKernelGGL(k_market, dim3(64), dim3(256), 0, stream, ws, out);
}